// Round 3
// baseline (9336.337 us; speedup 1.0000x reference)
//
#include <hip/hip_runtime.h>
#include <math.h>

#define T_SEQ 2048
#define DM 1024
#define NH 16
#define KD 64
#define MTOT 4096  // B * T_SEQ

// ---------------------------------------------------------------------------
// Dtype probe: scan first 4096 ushorts of Wq. bf16 inputs (|v| <= ~0.2) have
// exponent field <= ~0x7C. If inputs are really fp32, half the ushorts are
// fp32 mantissa bits -> random exponent fields; P(any >= 0xC0) ~= 1.
// flag=0 -> inputs are bf16; flag=1 -> inputs are fp32.
// ---------------------------------------------------------------------------
__global__ void detect_dtype(const unsigned short* __restrict__ w, int* flag) {
  __shared__ int s;
  if (threadIdx.x == 0) s = 0;
  __syncthreads();
  int bad = 0;
  for (int i = threadIdx.x; i < 4096; i += blockDim.x) {
    unsigned e = (w[i] >> 7) & 0xFF;
    if (e >= 0xC0) bad = 1;
  }
  if (bad) atomicOr(&s, 1);
  __syncthreads();
  if (threadIdx.x == 0) *flag = s;
}

// ---------------------------------------------------------------------------
// Naive GEMM: C[M,N] = A[M,K] @ W[K,N] + bias (row-major everywhere).
// One thread per output element, fp32 accumulation. Runs only if *flag==want.
// ---------------------------------------------------------------------------
template <typename T>
__global__ __launch_bounds__(256) void gemm_naive(
    const int* __restrict__ flag, int want,
    const T* __restrict__ A, const T* __restrict__ W,
    const T* __restrict__ bias, T* __restrict__ C, int M, int N, int K) {
  if (*flag != want) return;
  int idx = blockIdx.x * blockDim.x + threadIdx.x;
  if (idx >= M * N) return;
  int m = idx / N, n = idx % N;
  const T* a = A + (size_t)m * K;
  float acc = 0.f;
  for (int k = 0; k < K; ++k)
    acc += (float)a[k] * (float)W[(size_t)k * N + n];
  acc += (float)bias[n];
  C[idx] = (T)acc;
}

// ---------------------------------------------------------------------------
// Naive MQA attention. Q [b][t][h*64+d], K [b][t][d], V [b][t][d] row-major.
// One block per (q-row, head, batch); two-pass softmax with scores in LDS.
// ---------------------------------------------------------------------------
template <typename T>
__global__ __launch_bounds__(256) void attn_naive(
    const int* __restrict__ flag, int want,
    const T* __restrict__ Q, const T* __restrict__ Kp,
    const T* __restrict__ V, T* __restrict__ AO) {
  if (*flag != want) return;
  __shared__ float q[KD];
  __shared__ float sarr[T_SEQ];
  __shared__ float red[256];
  const int t = threadIdx.x;
  const int qi = blockIdx.x, h = blockIdx.y, b = blockIdx.z;

  const T* qrow = Q + ((size_t)(b * T_SEQ + qi)) * DM + h * KD;
  if (t < KD) q[t] = (float)qrow[t];
  __syncthreads();

  // scores (scaled by 1/sqrt(64) = 1/8)
  const T* Kb = Kp + (size_t)b * T_SEQ * KD;
  for (int key = t; key < T_SEQ; key += 256) {
    const T* kr = Kb + (size_t)key * KD;
    float s = 0.f;
    for (int d = 0; d < KD; ++d) s += q[d] * (float)kr[d];
    sarr[key] = s * 0.125f;
  }
  __syncthreads();

  // row max
  float lm = -3.0e38f;
  for (int key = t; key < T_SEQ; key += 256) lm = fmaxf(lm, sarr[key]);
  red[t] = lm;
  __syncthreads();
  for (int s2 = 128; s2 > 0; s2 >>= 1) {
    if (t < s2) red[t] = fmaxf(red[t], red[t + s2]);
    __syncthreads();
  }
  const float m = red[0];
  __syncthreads();

  // exp + sum
  float ls = 0.f;
  for (int key = t; key < T_SEQ; key += 256) {
    float p = expf(sarr[key] - m);
    sarr[key] = p;
    ls += p;
  }
  red[t] = ls;
  __syncthreads();
  for (int s2 = 128; s2 > 0; s2 >>= 1) {
    if (t < s2) red[t] += red[t + s2];
    __syncthreads();
  }
  const float l = red[0];  // >= 1 (max term contributes 1)
  __syncthreads();

  // P @ V: thread (d = t&63, chunk c = t>>6), chunk covers 512 keys
  const int d = t & 63, c = t >> 6;
  const T* Vb = V + (size_t)b * T_SEQ * KD;
  float o = 0.f;
  for (int key = c * 512; key < c * 512 + 512; ++key)
    o += sarr[key] * (float)Vb[(size_t)key * KD + d];
  red[t] = o;
  __syncthreads();
  if (c == 0) {
    float oo = red[d] + red[64 + d] + red[128 + d] + red[192 + d];
    AO[((size_t)(b * T_SEQ + qi)) * DM + h * KD + d] = (T)(oo / l);
  }
}

// ---------------------------------------------------------------------------
template <typename T>
static void run_pipeline(const int* flag, int want, void* const* d_in,
                         void* d_out, char* ws, hipStream_t stream) {
  const T* query = (const T*)d_in[0];
  const T* Wq = (const T*)d_in[1];
  const T* bq = (const T*)d_in[2];
  const T* Wk = (const T*)d_in[3];
  const T* bk = (const T*)d_in[4];
  const T* Wv = (const T*)d_in[5];
  const T* bv = (const T*)d_in[6];
  const T* Wo = (const T*)d_in[7];
  const T* bo = (const T*)d_in[8];
  T* out = (T*)d_out;

  // scratch (after 4 KB flag slot): K, V, AO sized for T
  T* Kw = (T*)(ws + 4096);
  T* Vw = (T*)(ws + 4096 + (size_t)MTOT * KD * sizeof(T));
  T* AOw = (T*)(ws + 4096 + (size_t)2 * MTOT * KD * sizeof(T));
  T* Qw = out;  // Q staged in d_out; consumed before final GEMM rewrites it

  gemm_naive<T><<<(MTOT * DM) / 256, 256, 0, stream>>>(flag, want, query, Wq, bq, Qw, MTOT, DM, DM);
  gemm_naive<T><<<(MTOT * KD) / 256, 256, 0, stream>>>(flag, want, query, Wk, bk, Kw, MTOT, KD, DM);
  gemm_naive<T><<<(MTOT * KD) / 256, 256, 0, stream>>>(flag, want, query, Wv, bv, Vw, MTOT, KD, DM);
  attn_naive<T><<<dim3(T_SEQ, NH, 2), 256, 0, stream>>>(flag, want, Qw, Kw, Vw, AOw);
  gemm_naive<T><<<(MTOT * DM) / 256, 256, 0, stream>>>(flag, want, AOw, Wo, bo, out, MTOT, DM, DM);
}

extern "C" void kernel_launch(void* const* d_in, const int* in_sizes, int n_in,
                              void* d_out, int out_size, void* d_ws, size_t ws_size,
                              hipStream_t stream) {
  char* ws = (char*)d_ws;
  int* flag = (int*)ws;

  detect_dtype<<<1, 256, 0, stream>>>((const unsigned short*)d_in[1], flag);
  run_pipeline<__bf16>(flag, 0, d_in, d_out, ws, stream);   // runs iff inputs bf16
  run_pipeline<float>(flag, 1, d_in, d_out, ws, stream);    // runs iff inputs fp32
}